// Round 5
// baseline (2159.118 us; speedup 1.0000x reference)
//
#include <hip/hip_runtime.h>

#define DEG 17
#define NSTEPS 32
#define HD 96

typedef float v2f __attribute__((ext_vector_type(2)));

#if __has_builtin(__builtin_elementwise_fma)
#define PFMA(a,b,c) __builtin_elementwise_fma(a,b,c)
#else
static __device__ __forceinline__ v2f PFMA(v2f a, v2f b, v2f c) {
  v2f r; r[0] = fmaf(a[0], b[0], c[0]); r[1] = fmaf(a[1], b[1], c[1]); return r;
}
#endif

// ---- workspace float offsets ----
#define WS_U0     0          // 196608
#define WS_BAR    196608     // 256 ints (16 counters spaced 16 apart)
#define WS_U1     196864     // 196608
#define WS_XIN    393472     // 98304
#define WS_GX     491776     // 393216
#define WS_LOSSP  884992     // 16384 floats (32 steps * 512)
#define WS_CNTP   901376     // 16384 ints

// ---- LDS layout (floats) ----
#define W1L   0        // 9216  [96][96]
#define W2L   9216     // 9216  [96][96]
#define MSGB  18432    // 288
#define M0B   18720    // 96
#define PRW   18816    // 768  pred_W [96][8]
#define VBASE 19584
#define VSTR  10272
// per-vblock relative offsets (2 nodes per vblock):
#define VZ1    0       // 3840 [96][40] k-major; overlays: PL[16][384]=6144, PU[32][192]=6144
#define VZ2    3840    // 3840 [96][40]
#define VGX    7680    // 768  [2][384]
#define VGATES 8448    // 768  [2][384]
#define VMSGH  9216    // 384  [192][2] (msg k=0..95 atomically accumulated, h k=96..191 persists)
#define VS3T   9600    // 192  [96][2]
#define VH2T   9792    // 192  [96][2]
#define VSLC   9984    // 192  [2][96] cell state (persistent)
#define VLGT   10176   // 32
#define VNBRI  10208   // 40 ints
#define BARC  (VBASE + 2*VSTR)   // 2 ints (vblock barrier counters)
#define SMTOT (BARC + 8)         // 40136 floats = 160544 B (<= 160 KiB)

// ---------------- init1: embedding + input MLP -> xin; u0 self-half = msg0_b
__global__ void init_kernel(
    const int* __restrict__ x,
    const float* __restrict__ digit_emb,
    const float* __restrict__ row_emb,
    const float* __restrict__ col_emb,
    const float* __restrict__ in0_W,
    const float* __restrict__ in0_b,
    const float* __restrict__ in_Ws,
    const float* __restrict__ in_bs,
    const float* __restrict__ msg0_b,
    float* __restrict__ xin,
    float* __restrict__ u0)
{
  const int node = blockIdx.x;
  const int j = threadIdx.x;
  const int n = node & 63;
  const int r = n >> 3, c = n & 7;
  __shared__ float feat[48];
  __shared__ float za[HD];
  __shared__ float zb[HD];
  if (j < 16)      feat[j] = digit_emb[x[node]*16 + j];
  else if (j < 32) feat[j] = row_emb[r*16 + (j-16)];
  else if (j < 48) feat[j] = col_emb[c*16 + (j-32)];
  u0[node*192 + 96 + j] = msg0_b[j];
  __syncthreads();
  float a = in0_b[j];
  for (int k = 0; k < 48; ++k) a = fmaf(feat[k], in0_W[k*HD + j], a);
  za[j] = fmaxf(a, 0.f);
  __syncthreads();
  a = in_bs[j];
  for (int k = 0; k < HD; ++k) a = fmaf(za[k], in_Ws[k*HD + j], a);
  zb[j] = fmaxf(a, 0.f);
  __syncthreads();
  a = in_bs[HD + j];
  for (int k = 0; k < HD; ++k) a = fmaf(zb[k], in_Ws[9216 + k*HD + j], a);
  za[j] = fmaxf(a, 0.f);
  __syncthreads();
  a = in_bs[2*HD + j];
  for (int k = 0; k < HD; ++k) a = fmaf(za[k], in_Ws[2*9216 + k*HD + j], a);
  xin[node*HD + j] = a;
}

// ---------------- init2: gx = xin @ W_ih[96:192] + b_ih + b_hh (one-time)
__global__ __launch_bounds__(384) void gx_kernel(
    const float* __restrict__ xin, const float* __restrict__ W_ih,
    const float* __restrict__ b_ih, const float* __restrict__ b_hh,
    float* __restrict__ gx)
{
  __shared__ float xs[4*HD];
  const int tid = threadIdx.x;
  const int base = blockIdx.x * 4;
  {
    const int m = tid / HD, k = tid - m*HD;
    xs[m*HD + k] = xin[(base+m)*HD + k];
  }
  __syncthreads();
  const int j = tid;  // 0..383
  float a0 = b_ih[j] + b_hh[j], a1 = a0, a2 = a0, a3 = a0;
  for (int k = 0; k < HD; ++k) {
    const float w = W_ih[(96+k)*384 + j];
    a0 = fmaf(xs[k], w, a0);
    a1 = fmaf(xs[HD+k], w, a1);
    a2 = fmaf(xs[2*HD+k], w, a2);
    a3 = fmaf(xs[3*HD+k], w, a3);
  }
  gx[(base+0)*384 + j] = a0;
  gx[(base+1)*384 + j] = a1;
  gx[(base+2)*384 + j] = a2;
  gx[(base+3)*384 + j] = a3;
}

// per-vblock barrier over 4 waves: LDS counter, monotonically increasing target
__device__ __forceinline__ void vbar(int* c, int want) {
  if ((threadIdx.x & 63) == 0)
    __hip_atomic_fetch_add(c, 1, __ATOMIC_RELEASE, __HIP_MEMORY_SCOPE_WORKGROUP);
  while (__hip_atomic_load(c, __ATOMIC_ACQUIRE, __HIP_MEMORY_SCOPE_WORKGROUP) < want)
    __builtin_amdgcn_s_sleep(1);
}

// ---------------- persistent solver: 256 blocks (1/CU), 2 vblocks of 4 waves ----------------
__global__ __launch_bounds__(512, 1) void solve_kernel(
    const int* __restrict__ edges,
    const float* __restrict__ msg0_W, const float* __restrict__ msg0_b,
    const float* __restrict__ msg_Ws, const float* __restrict__ msg_bs,
    const float* __restrict__ W_ih, const float* __restrict__ W_hh,
    const float* __restrict__ pred_W, const float* __restrict__ pred_b,
    const int* __restrict__ target,
    const float* __restrict__ gx,
    float* __restrict__ u0, float* __restrict__ u1,
    int* bar,
    float* __restrict__ lossP, int* __restrict__ cntP,
    float* __restrict__ final_pred_out)
{
  __shared__ float sm[SMTOT];

  const int tid = threadIdx.x;
  const int vb  = tid >> 8;          // vblock 0/1 (waves 0-3 / 4-7 -> 1 wave each per SIMD)
  const int vt  = tid & 255;         // thread-in-vblock
  const int blk = blockIdx.x;
  const int bb  = blk & 15;          // batch; blocks == bb (mod 16) -> same XCD under %8 round-robin
  const int grp = blk >> 4;
  const int gbase = bb*64 + grp*4 + vb*2;  // first node of vblock

  float* const vs = sm + VBASE + vb*VSTR;
  int* const vnbri = (int*)(vs + VNBRI);
  int* const vbc = (int*)(sm + BARC) + vb;

  // ===== one-time LDS fill =====
  for (int i = tid*4; i < 9216; i += 2048) {
    *(float4*)&sm[W1L + i] = *(const float4*)&msg_Ws[i];
    *(float4*)&sm[W2L + i] = *(const float4*)&msg_Ws[9216 + i];
  }
  if (tid < 288) sm[MSGB + tid] = msg_bs[tid];
  if (tid < 96)  sm[M0B + tid]  = msg0_b[tid];
  if (tid < 2)   ((int*)(sm + BARC))[tid] = 0;
  for (int i = tid; i < 768; i += 512) sm[PRW + i] = pred_W[i];   // full 96x8
  #pragma unroll
  for (int t = 0; t < 3; ++t) {
    const int idx = t*256 + vt;      // 0..767
    vs[VGX + idx] = gx[gbase*384 + idx];
  }
  if (vt < 192) {
    vs[VSLC + vt] = 0.f;             // cell state
    vs[VMSGH + 192 + vt] = 0.f;      // h slots (k=96..191)
  }
  if (vt < 40) {
    const int m = vt / 20, r = vt % 20;
    vnbri[vt] = (r < DEG) ? (bb*64 + edges[((grp*4 + vb*2) + m)*DEG + r])*192 : -1;
  }
  __syncthreads();

  const float* uP = u0;
  float*       uN = u1;
  int vph = 0;

  for (int st = 0; st < NSTEPS; ++st) {
    // ===== phase 1: z1 gather (240 thr) + s3t zero / msgh-msg pre-init (16 thr) =====
    if (vt < 240) {
      const int row = vt % 40;       // m*20 + r
      const int kh  = vt / 40;       // 0..5
      const int m = row / 20;
      const int k0 = kh * 16;
      const int nb = vnbri[row];
      if (nb >= 0) {
        const float* ue = uP + nb + k0;
        const float* us = uP + (gbase+m)*192 + 96 + k0;
        #pragma unroll
        for (int t = 0; t < 4; ++t) {
          const float4 a = *(const float4*)(ue + 4*t);
          const float4 b = *(const float4*)(us + 4*t);
          vs[VZ1 + (k0+4*t+0)*40 + row] = fmaxf(a.x + b.x, 0.f);
          vs[VZ1 + (k0+4*t+1)*40 + row] = fmaxf(a.y + b.y, 0.f);
          vs[VZ1 + (k0+4*t+2)*40 + row] = fmaxf(a.z + b.z, 0.f);
          vs[VZ1 + (k0+4*t+3)*40 + row] = fmaxf(a.w + b.w, 0.f);
        }
      } else {
        #pragma unroll
        for (int t = 0; t < 16; ++t) vs[VZ1 + (k0+t)*40 + row] = 0.f;
      }
    } else {
      const int i = vt - 240;        // 0..15
      #pragma unroll
      for (int t = 0; t < 12; ++t) vs[VS3T + i*12 + t] = 0.f;
      #pragma unroll
      for (int t = 0; t < 12; ++t) {          // msgh msg-half = 17*b3
        const int idx = i*12 + t;             // 0..191 == j*2+m
        vs[VMSGH + idx] = 17.f * sm[MSGB + 192 + (idx >> 1)];
      }
    }
    vph += 4; vbar(vbc, vph);

    // ===== phase 2: GEMM1 z2 = relu(z1 @ W1 + b1), LDS W, packed fma =====
    if (vt < 240) {
      const int jg = vt % 24, dg = vt / 24;   // 4 cols, 4 rows
      const int j4 = jg*4, d4 = dg*4;
      v2f acc[4][2] = {};
      #pragma unroll 4
      for (int k = 0; k < 96; ++k) {
        const float4 z = *(const float4*)&vs[VZ1 + k*40 + d4];
        const float4 w = *(const float4*)&sm[W1L + k*96 + j4];
        const v2f w01 = {w.x, w.y}, w23 = {w.z, w.w};
        const float ze[4] = {z.x, z.y, z.z, z.w};
        #pragma unroll
        for (int dd = 0; dd < 4; ++dd) {
          const v2f zz = {ze[dd], ze[dd]};
          acc[dd][0] = PFMA(zz, w01, acc[dd][0]);
          acc[dd][1] = PFMA(zz, w23, acc[dd][1]);
        }
      }
      #pragma unroll
      for (int jj = 0; jj < 4; ++jj) {
        const float b1 = sm[MSGB + j4 + jj];
        float4 q;
        q.x = fmaxf(acc[0][jj>>1][jj&1] + b1, 0.f);
        q.y = fmaxf(acc[1][jj>>1][jj&1] + b1, 0.f);
        q.z = fmaxf(acc[2][jj>>1][jj&1] + b1, 0.f);
        q.w = fmaxf(acc[3][jj>>1][jj&1] + b1, 0.f);
        *(float4*)&vs[VZ2 + (j4+jj)*40 + d4] = q;
      }
    }
    vph += 4; vbar(vbc, vph);

    // ===== phase 3: GEMM2 + relu + masked row-sum -> s3t, packed fma =====
    if (vt < 240) {
      const int jg = vt % 24, dg = vt / 24;
      const int j4 = jg*4, d4 = dg*4;
      v2f acc[4][2] = {};
      #pragma unroll 4
      for (int k = 0; k < 96; ++k) {
        const float4 z = *(const float4*)&vs[VZ2 + k*40 + d4];
        const float4 w = *(const float4*)&sm[W2L + k*96 + j4];
        const v2f w01 = {w.x, w.y}, w23 = {w.z, w.w};
        const float ze[4] = {z.x, z.y, z.z, z.w};
        #pragma unroll
        for (int dd = 0; dd < 4; ++dd) {
          const v2f zz = {ze[dd], ze[dd]};
          acc[dd][0] = PFMA(zz, w01, acc[dd][0]);
          acc[dd][1] = PFMA(zz, w23, acc[dd][1]);
        }
      }
      const int nd = d4 / 20;        // rows d4..d4+3 never straddle a node
      const int r0 = d4 - nd*20;
      #pragma unroll
      for (int jj = 0; jj < 4; ++jj) {
        const float b2 = sm[MSGB + 96 + j4 + jj];
        float p = 0.f;
        #pragma unroll
        for (int dd = 0; dd < 4; ++dd)
          if (r0 + dd < DEG) p += fmaxf(acc[dd][jj>>1][jj&1] + b2, 0.f);
        atomicAdd(&vs[VS3T + (j4+jj)*2 + nd], p);
      }
    }
    vph += 4; vbar(vbc, vph);

    // ===== phase 4: GEMM3 msg += s3 @ W3 via LDS atomics (msgh pre-inited) =====
    if (vt < 192) {
      const int jg = vt % 24, kq = vt / 24;   // kq 0..7, 12 k each
      const int j4 = jg*4, k0 = kq*12;
      const float* W3 = msg_Ws + 2*9216;
      v2f acc[2][2] = {};
      #pragma unroll
      for (int kk = 0; kk < 12; ++kk) {
        const int k = k0 + kk;
        const float2 sv = *(const float2*)&vs[VS3T + k*2];
        const float4 wv = *(const float4*)&W3[k*96 + j4];
        const v2f w01 = {wv.x, wv.y}, w23 = {wv.z, wv.w};
        const v2f s0 = {sv.x, sv.x}, s1 = {sv.y, sv.y};
        acc[0][0] = PFMA(s0, w01, acc[0][0]);
        acc[0][1] = PFMA(s0, w23, acc[0][1]);
        acc[1][0] = PFMA(s1, w01, acc[1][0]);
        acc[1][1] = PFMA(s1, w23, acc[1][1]);
      }
      #pragma unroll
      for (int m = 0; m < 2; ++m)
        #pragma unroll
        for (int jj = 0; jj < 4; ++jj)
          atomicAdd(&vs[VMSGH + (j4+jj)*2 + m], acc[m][jj>>1][jj&1]);
    }
    vph += 4; vbar(vbc, vph);

    // ===== phase 5: LSTM GEMM gates = [msg|h] @ [Wih;Whh] + gx (float4 W, packed fma) =====
    {
      const int jg = vt & 31, kq = vt >> 5;   // j12 cols, kq 0..7 x 24k
      const int j12 = jg*12, k0 = kq*24;
      const float* Wb = (kq < 4) ? (W_ih + (size_t)k0*384 + j12)
                                 : (W_hh + (size_t)(k0-96)*384 + j12);
      v2f acc[2][6] = {};
      #pragma unroll 4
      for (int kk = 0; kk < 24; ++kk) {
        const float2 iv = *(const float2*)&vs[VMSGH + (k0+kk)*2];
        const float* wp = Wb + kk*384;
        const float4 wa = *(const float4*)wp;
        const float4 wm = *(const float4*)(wp + 4);
        const float4 wc = *(const float4*)(wp + 8);
        const v2f w0 = {wa.x, wa.y}, w1 = {wa.z, wa.w};
        const v2f w2 = {wm.x, wm.y}, w3 = {wm.z, wm.w};
        const v2f w4 = {wc.x, wc.y}, w5 = {wc.z, wc.w};
        const v2f i0 = {iv.x, iv.x}, i1 = {iv.y, iv.y};
        acc[0][0] = PFMA(i0, w0, acc[0][0]);
        acc[0][1] = PFMA(i0, w1, acc[0][1]);
        acc[0][2] = PFMA(i0, w2, acc[0][2]);
        acc[0][3] = PFMA(i0, w3, acc[0][3]);
        acc[0][4] = PFMA(i0, w4, acc[0][4]);
        acc[0][5] = PFMA(i0, w5, acc[0][5]);
        acc[1][0] = PFMA(i1, w0, acc[1][0]);
        acc[1][1] = PFMA(i1, w1, acc[1][1]);
        acc[1][2] = PFMA(i1, w2, acc[1][2]);
        acc[1][3] = PFMA(i1, w3, acc[1][3]);
        acc[1][4] = PFMA(i1, w4, acc[1][4]);
        acc[1][5] = PFMA(i1, w5, acc[1][5]);
      }
      #pragma unroll
      for (int m = 0; m < 2; ++m) {
        float4 qa = {acc[m][0][0], acc[m][0][1], acc[m][1][0], acc[m][1][1]};
        float4 qb = {acc[m][2][0], acc[m][2][1], acc[m][3][0], acc[m][3][1]};
        float4 qc = {acc[m][4][0], acc[m][4][1], acc[m][5][0], acc[m][5][1]};
        *(float4*)&vs[VZ1 + (kq*2 + m)*384 + j12]     = qa;   // PL overlay
        *(float4*)&vs[VZ1 + (kq*2 + m)*384 + j12 + 4] = qb;
        *(float4*)&vs[VZ1 + (kq*2 + m)*384 + j12 + 8] = qc;
      }
    }
    vph += 4; vbar(vbc, vph);
    {
      #pragma unroll
      for (int t = 0; t < 3; ++t) {
        const int idx = t*256 + vt;            // 0..767 == m*384+j
        const int m = idx / 384, j = idx - m*384;
        float gv = vs[VGX + idx];
        #pragma unroll
        for (int kq = 0; kq < 8; ++kq) gv += vs[VZ1 + (kq*2 + m)*384 + j];
        vs[VGATES + idx] = gv;
      }
    }
    vph += 4; vbar(vbc, vph);

    // ===== phase 6: pointwise LSTM (h,s stay in LDS) =====
    if (vt < 192) {
      const int m = vt / 96, hj = vt - m*96;
      const float gi = vs[VGATES + m*384 + hj];
      const float gf = vs[VGATES + m*384 + 96 + hj];
      const float gg = vs[VGATES + m*384 + 192 + hj];
      const float go = vs[VGATES + m*384 + 288 + hj];
      const float sv = vs[VSLC + vt];
      const float ig = 1.f/(1.f + expf(-gi));
      const float fg = 1.f/(1.f + expf(-gf));
      const float cg = tanhf(gg);
      const float og = 1.f/(1.f + expf(-go));
      const float s2 = fg*sv + ig*cg;
      const float h2 = og*tanhf(s2);
      vs[VSLC + vt] = s2;
      vs[VH2T + hj*2 + m] = h2;
      vs[VMSGH + (96+hj)*2 + m] = h2;   // h for next step's LSTM GEMM
    }
    vph += 4; vbar(vbc, vph);

    // ===== phase 7: u_next = h2 @ [W0_edge | W0_self] (float4 W, packed fma) =====
    {
      const int jg = vt & 15, kq = vt >> 4;   // j12 cols (192), kq 0..15 x 6k
      const int j12 = jg*12, k0 = kq*6;
      const float* Wb = (j12 < 96) ? (msg0_W + j12) : (msg0_W + 9216 + j12 - 96);
      v2f acc[2][6] = {};
      #pragma unroll
      for (int kk = 0; kk < 6; ++kk) {
        const int k = k0 + kk;
        const float2 iv = *(const float2*)&vs[VH2T + k*2];
        const float* wp = Wb + k*96;
        const float4 wa = *(const float4*)wp;
        const float4 wm = *(const float4*)(wp + 4);
        const float4 wc = *(const float4*)(wp + 8);
        const v2f w0 = {wa.x, wa.y}, w1 = {wa.z, wa.w};
        const v2f w2 = {wm.x, wm.y}, w3 = {wm.z, wm.w};
        const v2f w4 = {wc.x, wc.y}, w5 = {wc.z, wc.w};
        const v2f i0 = {iv.x, iv.x}, i1 = {iv.y, iv.y};
        acc[0][0] = PFMA(i0, w0, acc[0][0]);
        acc[0][1] = PFMA(i0, w1, acc[0][1]);
        acc[0][2] = PFMA(i0, w2, acc[0][2]);
        acc[0][3] = PFMA(i0, w3, acc[0][3]);
        acc[0][4] = PFMA(i0, w4, acc[0][4]);
        acc[0][5] = PFMA(i0, w5, acc[0][5]);
        acc[1][0] = PFMA(i1, w0, acc[1][0]);
        acc[1][1] = PFMA(i1, w1, acc[1][1]);
        acc[1][2] = PFMA(i1, w2, acc[1][2]);
        acc[1][3] = PFMA(i1, w3, acc[1][3]);
        acc[1][4] = PFMA(i1, w4, acc[1][4]);
        acc[1][5] = PFMA(i1, w5, acc[1][5]);
      }
      #pragma unroll
      for (int m = 0; m < 2; ++m) {
        float4 qa = {acc[m][0][0], acc[m][0][1], acc[m][1][0], acc[m][1][1]};
        float4 qb = {acc[m][2][0], acc[m][2][1], acc[m][3][0], acc[m][3][1]};
        float4 qc = {acc[m][4][0], acc[m][4][1], acc[m][5][0], acc[m][5][1]};
        *(float4*)&vs[VZ1 + (kq*2 + m)*192 + j12]     = qa;   // PU overlay
        *(float4*)&vs[VZ1 + (kq*2 + m)*192 + j12 + 4] = qb;
        *(float4*)&vs[VZ1 + (kq*2 + m)*192 + j12 + 8] = qc;
      }
    }
    vph += 4; vbar(vbc, vph);
    if (vt < 192) {
      #pragma unroll
      for (int t = 0; t < 2; ++t) {
        const int idx = t*192 + vt;            // 0..383
        const int m = idx / 192, j = idx - m*192;
        float v = (j >= 96) ? sm[M0B + j - 96] : 0.f;   // fold b0 into self half
        #pragma unroll
        for (int kq = 0; kq < 16; ++kq) v += vs[VZ1 + (kq*2 + m)*192 + j];
        uN[(gbase+m)*192 + j] = v;
      }
    } else {
      // pred head partials (wave 3 of vblock; h2t stable since phase 6; pred_W in LDS)
      const int t2 = vt - 192;
      const int m = t2 >> 5, c = (t2 >> 2) & 7, kq2 = t2 & 3;
      float p = 0.f;
      #pragma unroll
      for (int kk = 0; kk < 24; ++kk) {
        const int k = kq2*24 + kk;
        p = fmaf(vs[VH2T + k*2 + m], sm[PRW + k*8 + c], p);
      }
      p += __shfl_xor(p, 1);
      p += __shfl_xor(p, 2);
      if (kq2 == 0) vs[VLGT + m*8 + c] = p + pred_b[c];
    }
    __threadfence();                 // per-thread: uN stores agent-visible before arrive
    vph += 4; vbar(vbc, vph);

    // ===== phase 8: softmax/loss/pred (runs in the arrive window) =====
    if (vt < 2) {
      const int m = vt;
      const int node = gbase + m;
      float mx = vs[VLGT + m*8];
      int pred = 0;
      #pragma unroll
      for (int c = 1; c < 8; ++c) {
        const float v = vs[VLGT + m*8 + c];
        if (v > mx) { mx = v; pred = c; }
      }
      float sum = 0.f;
      #pragma unroll
      for (int c = 0; c < 8; ++c) sum += expf(vs[VLGT + m*8 + c] - mx);
      const float lse = mx + logf(sum);
      const int tgt = target[node] - 1;
      vs[VLGT + 16 + m] = lse - vs[VLGT + m*8 + tgt];
      vs[VLGT + 20 + m] = (pred == tgt) ? 1.f : 0.f;
      if (st == NSTEPS-1) final_pred_out[node] = (float)pred;
      if (m == 0) {
        // lanes 0,1 of this wave wrote above; in-wave instruction order makes this safe
        lossP[st*512 + bb*32 + grp*2 + vb] = vs[VLGT+16] + vs[VLGT+17];
        cntP[st*512 + bb*32 + grp*2 + vb] = (int)(vs[VLGT+20] + vs[VLGT+21]);
      }
    }

    // ===== per-batch barrier (32 vblocks), per-vblock arrive/wait =====
    if (st < NSTEPS-1) {
      if (vt == 0) {
        __hip_atomic_fetch_add(&bar[bb*16], 1, __ATOMIC_RELEASE, __HIP_MEMORY_SCOPE_AGENT);
        const int want = 32*(st+1);
        while (__hip_atomic_load(&bar[bb*16], __ATOMIC_RELAXED, __HIP_MEMORY_SCOPE_AGENT) < want)
          __builtin_amdgcn_s_sleep(2);
        __threadfence();   // acquire before reading peers' u
      }
      vph += 4; vbar(vbc, vph);
      const float* tp = uP; uP = uN; uN = (float*)tp;
    }
  }
}

// ---------------- finalize: accs + loss ----------------
__global__ void finalize_kernel(const float* __restrict__ lossP,
                                const int* __restrict__ cntP,
                                float* __restrict__ out)
{
  __shared__ float sl[32];
  const int tid = threadIdx.x;   // 256
  const int st = tid >> 3, q = tid & 7;
  float lsum = 0.f;
  for (int i = 0; i < 64; ++i) lsum += lossP[st*512 + q*64 + i];
  lsum += __shfl_xor(lsum, 1);
  lsum += __shfl_xor(lsum, 2);
  lsum += __shfl_xor(lsum, 4);
  if (q == 0) sl[st] = lsum;
  float okc = 0.f;
  #pragma unroll
  for (int t = 0; t < 2; ++t) {
    const int bbat = q + 8*t;                    // batch id
    int c = 0;
    for (int i = 0; i < 32; ++i) c += cntP[st*512 + bbat*32 + i];
    okc += (c == 64) ? 1.f : 0.f;
  }
  okc += __shfl_xor(okc, 1);
  okc += __shfl_xor(okc, 2);
  okc += __shfl_xor(okc, 4);
  if (q == 0) out[1 + st] = okc / 16.f;
  __syncthreads();
  if (tid == 0) {
    float tot = 0.f;
    for (int i = 0; i < 32; ++i) tot += sl[i];
    out[0] = tot / (1024.f * (float)NSTEPS);
  }
}

extern "C" void kernel_launch(void* const* d_in, const int* in_sizes, int n_in,
                              void* d_out, int out_size, void* d_ws, size_t ws_size,
                              hipStream_t stream) {
  const int*   x         = (const int*)  d_in[0];
  const int*   target    = (const int*)  d_in[1];
  const int*   edges     = (const int*)  d_in[2];
  const float* digit_emb = (const float*)d_in[3];
  const float* row_emb   = (const float*)d_in[4];
  const float* col_emb   = (const float*)d_in[5];
  const float* in0_W     = (const float*)d_in[6];
  const float* in0_b     = (const float*)d_in[7];
  const float* in_Ws     = (const float*)d_in[8];
  const float* in_bs     = (const float*)d_in[9];
  const float* msg0_W    = (const float*)d_in[10];
  const float* msg0_b    = (const float*)d_in[11];
  const float* msg_Ws    = (const float*)d_in[12];
  const float* msg_bs    = (const float*)d_in[13];
  const float* W_ih      = (const float*)d_in[14];
  const float* W_hh      = (const float*)d_in[15];
  const float* b_ih      = (const float*)d_in[16];
  const float* b_hh      = (const float*)d_in[17];
  const float* pred_W    = (const float*)d_in[18];
  const float* pred_b    = (const float*)d_in[19];

  float* ws    = (float*)d_ws;
  float* u0    = ws + WS_U0;
  int*   bar   = (int*)(ws + WS_BAR);
  float* u1    = ws + WS_U1;
  float* xin   = ws + WS_XIN;
  float* gxb   = ws + WS_GX;
  float* lossP = ws + WS_LOSSP;
  int*   cntP  = (int*)(ws + WS_CNTP);

  // zero u0 (edge halves) + barrier counters; everything else fully written
  hipMemsetAsync(d_ws, 0, (size_t)(196608 + 256)*sizeof(float), stream);

  init_kernel<<<1024, HD, 0, stream>>>(x, digit_emb, row_emb, col_emb,
                                       in0_W, in0_b, in_Ws, in_bs,
                                       msg0_b, xin, u0);
  gx_kernel<<<256, 384, 0, stream>>>(xin, W_ih, b_ih, b_hh, gxb);

  float* outp = (float*)d_out;
  solve_kernel<<<256, 512, 0, stream>>>(
      edges, msg0_W, msg0_b, msg_Ws, msg_bs,
      W_ih, W_hh, pred_W, pred_b, target, gxb,
      u0, u1, bar, lossP, cntP, outp + 1 + NSTEPS);

  finalize_kernel<<<1, 256, 0, stream>>>(lossP, cntP, outp);
}

// Round 6
// 1189.221 us; speedup vs baseline: 1.8156x; 1.8156x over previous
//
#include <hip/hip_runtime.h>

#define DEG 17
#define NSTEPS 32
#define HD 96

typedef float v2f __attribute__((ext_vector_type(2)));

#if __has_builtin(__builtin_elementwise_fma)
#define PFMA(a,b,c) __builtin_elementwise_fma(a,b,c)
#else
static __device__ __forceinline__ v2f PFMA(v2f a, v2f b, v2f c) {
  v2f r; r[0] = fmaf(a[0], b[0], c[0]); r[1] = fmaf(a[1], b[1], c[1]); return r;
}
#endif

// ---- workspace float offsets ----
#define WS_U0     0          // 196608
#define WS_BAR    196608     // 256 ints (16 counters spaced 16 apart)
#define WS_U1     196864     // 196608
#define WS_XIN    393472     // 98304
#define WS_GX     491776     // 393216
#define WS_LOSSP  884992     // 16384 floats (32 steps * 512)
#define WS_CNTP   901376     // 16384 ints

// ---- LDS layout (floats) ----
#define W1L   0        // 9216  [96][96]
#define W2L   9216     // 9216  [96][96]
#define MSGB  18432    // 288
#define M0B   18720    // 96
#define PRW   18816    // 768  pred_W [96][8]
#define VBASE 19584
#define VSTR  10272
// per-vblock relative offsets (2 nodes per vblock):
#define VZ1    0       // 3840 [96][40] k-major; overlays: PL[16][384]=6144, PU[32][192]=6144
#define VZ2    3840    // 3840 [96][40]
#define VGX    7680    // 768  [2][384]
#define VGATES 8448    // 768  [2][384]
#define VMSGH  9216    // 384  [192][2] (msg k=0..95 atomically accumulated, h k=96..191 persists)
#define VS3T   9600    // 192  [96][2]
#define VH2T   9792    // 192  [96][2]
#define VSLC   9984    // 192  [2][96] cell state (persistent)
#define VLGT   10176   // 32
#define VNBRI  10208   // 40 ints
#define BARC  (VBASE + 2*VSTR)   // 2 ints (vblock barrier counters)
#define SMTOT (BARC + 8)         // 40136 floats = 160544 B (<= 160 KiB)

// ---------------- init1: embedding + input MLP -> xin; u0 self-half = msg0_b
__global__ void init_kernel(
    const int* __restrict__ x,
    const float* __restrict__ digit_emb,
    const float* __restrict__ row_emb,
    const float* __restrict__ col_emb,
    const float* __restrict__ in0_W,
    const float* __restrict__ in0_b,
    const float* __restrict__ in_Ws,
    const float* __restrict__ in_bs,
    const float* __restrict__ msg0_b,
    float* __restrict__ xin,
    float* __restrict__ u0)
{
  const int node = blockIdx.x;
  const int j = threadIdx.x;
  const int n = node & 63;
  const int r = n >> 3, c = n & 7;
  __shared__ float feat[48];
  __shared__ float za[HD];
  __shared__ float zb[HD];
  if (j < 16)      feat[j] = digit_emb[x[node]*16 + j];
  else if (j < 32) feat[j] = row_emb[r*16 + (j-16)];
  else if (j < 48) feat[j] = col_emb[c*16 + (j-32)];
  u0[node*192 + 96 + j] = msg0_b[j];
  __syncthreads();
  float a = in0_b[j];
  for (int k = 0; k < 48; ++k) a = fmaf(feat[k], in0_W[k*HD + j], a);
  za[j] = fmaxf(a, 0.f);
  __syncthreads();
  a = in_bs[j];
  for (int k = 0; k < HD; ++k) a = fmaf(za[k], in_Ws[k*HD + j], a);
  zb[j] = fmaxf(a, 0.f);
  __syncthreads();
  a = in_bs[HD + j];
  for (int k = 0; k < HD; ++k) a = fmaf(zb[k], in_Ws[9216 + k*HD + j], a);
  za[j] = fmaxf(a, 0.f);
  __syncthreads();
  a = in_bs[2*HD + j];
  for (int k = 0; k < HD; ++k) a = fmaf(za[k], in_Ws[2*9216 + k*HD + j], a);
  xin[node*HD + j] = a;
}

// ---------------- init2: gx = xin @ W_ih[96:192] + b_ih + b_hh (one-time)
__global__ __launch_bounds__(384) void gx_kernel(
    const float* __restrict__ xin, const float* __restrict__ W_ih,
    const float* __restrict__ b_ih, const float* __restrict__ b_hh,
    float* __restrict__ gx)
{
  __shared__ float xs[4*HD];
  const int tid = threadIdx.x;
  const int base = blockIdx.x * 4;
  {
    const int m = tid / HD, k = tid - m*HD;
    xs[m*HD + k] = xin[(base+m)*HD + k];
  }
  __syncthreads();
  const int j = tid;  // 0..383
  float a0 = b_ih[j] + b_hh[j], a1 = a0, a2 = a0, a3 = a0;
  for (int k = 0; k < HD; ++k) {
    const float w = W_ih[(96+k)*384 + j];
    a0 = fmaf(xs[k], w, a0);
    a1 = fmaf(xs[HD+k], w, a1);
    a2 = fmaf(xs[2*HD+k], w, a2);
    a3 = fmaf(xs[3*HD+k], w, a3);
  }
  gx[(base+0)*384 + j] = a0;
  gx[(base+1)*384 + j] = a1;
  gx[(base+2)*384 + j] = a2;
  gx[(base+3)*384 + j] = a3;
}

// per-vblock barrier over 4 waves: LDS counter, monotonically increasing target
__device__ __forceinline__ void vbar(int* c, int want) {
  if ((threadIdx.x & 63) == 0)
    __hip_atomic_fetch_add(c, 1, __ATOMIC_RELEASE, __HIP_MEMORY_SCOPE_WORKGROUP);
  while (__hip_atomic_load(c, __ATOMIC_ACQUIRE, __HIP_MEMORY_SCOPE_WORKGROUP) < want)
    __builtin_amdgcn_s_sleep(1);
}

// ---------------- persistent solver: 256 blocks (1/CU), 2 vblocks of 4 waves ----------------
__global__ __launch_bounds__(512, 1) void solve_kernel(
    const int* __restrict__ edges,
    const float* __restrict__ msg0_W, const float* __restrict__ msg0_b,
    const float* __restrict__ msg_Ws, const float* __restrict__ msg_bs,
    const float* __restrict__ W_ih, const float* __restrict__ W_hh,
    const float* __restrict__ pred_W, const float* __restrict__ pred_b,
    const int* __restrict__ target,
    const float* __restrict__ gx,
    float* __restrict__ u0, float* __restrict__ u1,
    int* bar,
    float* __restrict__ lossP, int* __restrict__ cntP,
    float* __restrict__ final_pred_out)
{
  __shared__ float sm[SMTOT];

  const int tid = threadIdx.x;
  const int vb  = tid >> 8;          // vblock 0/1 (waves 0-3 / 4-7 -> 1 wave each per SIMD)
  const int vt  = tid & 255;         // thread-in-vblock
  const int blk = blockIdx.x;
  const int bb  = blk & 15;          // batch; blocks == bb (mod 16) -> same XCD under %8 round-robin
  const int grp = blk >> 4;
  const int gbase = bb*64 + grp*4 + vb*2;  // first node of vblock

  float* const vs = sm + VBASE + vb*VSTR;
  int* const vnbri = (int*)(vs + VNBRI);
  int* const vbc = (int*)(sm + BARC) + vb;

  // ===== one-time LDS fill =====
  for (int i = tid*4; i < 9216; i += 2048) {
    *(float4*)&sm[W1L + i] = *(const float4*)&msg_Ws[i];
    *(float4*)&sm[W2L + i] = *(const float4*)&msg_Ws[9216 + i];
  }
  if (tid < 288) sm[MSGB + tid] = msg_bs[tid];
  if (tid < 96)  sm[M0B + tid]  = msg0_b[tid];
  if (tid < 2)   ((int*)(sm + BARC))[tid] = 0;
  for (int i = tid; i < 768; i += 512) sm[PRW + i] = pred_W[i];   // full 96x8
  #pragma unroll
  for (int t = 0; t < 3; ++t) {
    const int idx = t*256 + vt;      // 0..767
    vs[VGX + idx] = gx[gbase*384 + idx];
  }
  if (vt < 192) {
    vs[VSLC + vt] = 0.f;             // cell state
    vs[VMSGH + 192 + vt] = 0.f;      // h slots (k=96..191)
  }
  if (vt < 40) {
    const int m = vt / 20, r = vt % 20;
    vnbri[vt] = (r < DEG) ? (bb*64 + edges[((grp*4 + vb*2) + m)*DEG + r])*192 : -1;
  }
  __syncthreads();

  const float* uP = u0;
  float*       uN = u1;
  int vph = 0;

  for (int st = 0; st < NSTEPS; ++st) {
    // ===== phase 1: z1 gather (240 thr) + s3t zero / msgh-msg pre-init (16 thr) =====
    if (vt < 240) {
      const int row = vt % 40;       // m*20 + r
      const int kh  = vt / 40;       // 0..5
      const int m = row / 20;
      const int k0 = kh * 16;
      const int nb = vnbri[row];
      if (nb >= 0) {
        const float* ue = uP + nb + k0;
        const float* us = uP + (gbase+m)*192 + 96 + k0;
        #pragma unroll
        for (int t = 0; t < 4; ++t) {
          const float4 a = *(const float4*)(ue + 4*t);
          const float4 b = *(const float4*)(us + 4*t);
          vs[VZ1 + (k0+4*t+0)*40 + row] = fmaxf(a.x + b.x, 0.f);
          vs[VZ1 + (k0+4*t+1)*40 + row] = fmaxf(a.y + b.y, 0.f);
          vs[VZ1 + (k0+4*t+2)*40 + row] = fmaxf(a.z + b.z, 0.f);
          vs[VZ1 + (k0+4*t+3)*40 + row] = fmaxf(a.w + b.w, 0.f);
        }
      } else {
        #pragma unroll
        for (int t = 0; t < 16; ++t) vs[VZ1 + (k0+t)*40 + row] = 0.f;
      }
    } else {
      const int i = vt - 240;        // 0..15
      #pragma unroll
      for (int t = 0; t < 12; ++t) vs[VS3T + i*12 + t] = 0.f;
      #pragma unroll
      for (int t = 0; t < 12; ++t) {          // msgh msg-half = 17*b3
        const int idx = i*12 + t;             // 0..191 == j*2+m
        vs[VMSGH + idx] = 17.f * sm[MSGB + 192 + (idx >> 1)];
      }
    }
    vph += 4; vbar(vbc, vph);

    // ===== phase 2: GEMM1 z2 = relu(z1 @ W1 + b1), LDS W, packed fma =====
    if (vt < 240) {
      const int jg = vt % 24, dg = vt / 24;   // 4 cols, 4 rows
      const int j4 = jg*4, d4 = dg*4;
      v2f acc[4][2] = {};
      #pragma unroll 4
      for (int k = 0; k < 96; ++k) {
        const float4 z = *(const float4*)&vs[VZ1 + k*40 + d4];
        const float4 w = *(const float4*)&sm[W1L + k*96 + j4];
        const v2f w01 = {w.x, w.y}, w23 = {w.z, w.w};
        const float ze[4] = {z.x, z.y, z.z, z.w};
        #pragma unroll
        for (int dd = 0; dd < 4; ++dd) {
          const v2f zz = {ze[dd], ze[dd]};
          acc[dd][0] = PFMA(zz, w01, acc[dd][0]);
          acc[dd][1] = PFMA(zz, w23, acc[dd][1]);
        }
      }
      #pragma unroll
      for (int jj = 0; jj < 4; ++jj) {
        const float b1 = sm[MSGB + j4 + jj];
        float4 q;
        q.x = fmaxf(acc[0][jj>>1][jj&1] + b1, 0.f);
        q.y = fmaxf(acc[1][jj>>1][jj&1] + b1, 0.f);
        q.z = fmaxf(acc[2][jj>>1][jj&1] + b1, 0.f);
        q.w = fmaxf(acc[3][jj>>1][jj&1] + b1, 0.f);
        *(float4*)&vs[VZ2 + (j4+jj)*40 + d4] = q;
      }
    }
    vph += 4; vbar(vbc, vph);

    // ===== phase 3: GEMM2 + relu + masked row-sum -> s3t, packed fma =====
    if (vt < 240) {
      const int jg = vt % 24, dg = vt / 24;
      const int j4 = jg*4, d4 = dg*4;
      v2f acc[4][2] = {};
      #pragma unroll 4
      for (int k = 0; k < 96; ++k) {
        const float4 z = *(const float4*)&vs[VZ2 + k*40 + d4];
        const float4 w = *(const float4*)&sm[W2L + k*96 + j4];
        const v2f w01 = {w.x, w.y}, w23 = {w.z, w.w};
        const float ze[4] = {z.x, z.y, z.z, z.w};
        #pragma unroll
        for (int dd = 0; dd < 4; ++dd) {
          const v2f zz = {ze[dd], ze[dd]};
          acc[dd][0] = PFMA(zz, w01, acc[dd][0]);
          acc[dd][1] = PFMA(zz, w23, acc[dd][1]);
        }
      }
      const int nd = d4 / 20;        // rows d4..d4+3 never straddle a node
      const int r0 = d4 - nd*20;
      #pragma unroll
      for (int jj = 0; jj < 4; ++jj) {
        const float b2 = sm[MSGB + 96 + j4 + jj];
        float p = 0.f;
        #pragma unroll
        for (int dd = 0; dd < 4; ++dd)
          if (r0 + dd < DEG) p += fmaxf(acc[dd][jj>>1][jj&1] + b2, 0.f);
        atomicAdd(&vs[VS3T + (j4+jj)*2 + nd], p);
      }
    }
    vph += 4; vbar(vbc, vph);

    // ===== phase 4: GEMM3 msg += s3 @ W3 via LDS atomics (msgh pre-inited) =====
    if (vt < 192) {
      const int jg = vt % 24, kq = vt / 24;   // kq 0..7, 12 k each
      const int j4 = jg*4, k0 = kq*12;
      const float* W3 = msg_Ws + 2*9216;
      v2f acc[2][2] = {};
      #pragma unroll
      for (int kk = 0; kk < 12; ++kk) {
        const int k = k0 + kk;
        const float2 sv = *(const float2*)&vs[VS3T + k*2];
        const float4 wv = *(const float4*)&W3[k*96 + j4];
        const v2f w01 = {wv.x, wv.y}, w23 = {wv.z, wv.w};
        const v2f s0 = {sv.x, sv.x}, s1 = {sv.y, sv.y};
        acc[0][0] = PFMA(s0, w01, acc[0][0]);
        acc[0][1] = PFMA(s0, w23, acc[0][1]);
        acc[1][0] = PFMA(s1, w01, acc[1][0]);
        acc[1][1] = PFMA(s1, w23, acc[1][1]);
      }
      #pragma unroll
      for (int m = 0; m < 2; ++m)
        #pragma unroll
        for (int jj = 0; jj < 4; ++jj)
          atomicAdd(&vs[VMSGH + (j4+jj)*2 + m], acc[m][jj>>1][jj&1]);
    }
    vph += 4; vbar(vbc, vph);

    // ===== phase 5: LSTM GEMM gates = [msg|h] @ [Wih;Whh] + gx (float4 W, packed fma) =====
    {
      const int jg = vt & 31, kq = vt >> 5;   // j12 cols, kq 0..7 x 24k
      const int j12 = jg*12, k0 = kq*24;
      const float* Wb = (kq < 4) ? (W_ih + (size_t)k0*384 + j12)
                                 : (W_hh + (size_t)(k0-96)*384 + j12);
      v2f acc[2][6] = {};
      #pragma unroll 4
      for (int kk = 0; kk < 24; ++kk) {
        const float2 iv = *(const float2*)&vs[VMSGH + (k0+kk)*2];
        const float* wp = Wb + kk*384;
        const float4 wa = *(const float4*)wp;
        const float4 wm = *(const float4*)(wp + 4);
        const float4 wc = *(const float4*)(wp + 8);
        const v2f w0 = {wa.x, wa.y}, w1 = {wa.z, wa.w};
        const v2f w2 = {wm.x, wm.y}, w3 = {wm.z, wm.w};
        const v2f w4 = {wc.x, wc.y}, w5 = {wc.z, wc.w};
        const v2f i0 = {iv.x, iv.x}, i1 = {iv.y, iv.y};
        acc[0][0] = PFMA(i0, w0, acc[0][0]);
        acc[0][1] = PFMA(i0, w1, acc[0][1]);
        acc[0][2] = PFMA(i0, w2, acc[0][2]);
        acc[0][3] = PFMA(i0, w3, acc[0][3]);
        acc[0][4] = PFMA(i0, w4, acc[0][4]);
        acc[0][5] = PFMA(i0, w5, acc[0][5]);
        acc[1][0] = PFMA(i1, w0, acc[1][0]);
        acc[1][1] = PFMA(i1, w1, acc[1][1]);
        acc[1][2] = PFMA(i1, w2, acc[1][2]);
        acc[1][3] = PFMA(i1, w3, acc[1][3]);
        acc[1][4] = PFMA(i1, w4, acc[1][4]);
        acc[1][5] = PFMA(i1, w5, acc[1][5]);
      }
      #pragma unroll
      for (int m = 0; m < 2; ++m) {
        float4 qa = {acc[m][0][0], acc[m][0][1], acc[m][1][0], acc[m][1][1]};
        float4 qb = {acc[m][2][0], acc[m][2][1], acc[m][3][0], acc[m][3][1]};
        float4 qc = {acc[m][4][0], acc[m][4][1], acc[m][5][0], acc[m][5][1]};
        *(float4*)&vs[VZ1 + (kq*2 + m)*384 + j12]     = qa;   // PL overlay
        *(float4*)&vs[VZ1 + (kq*2 + m)*384 + j12 + 4] = qb;
        *(float4*)&vs[VZ1 + (kq*2 + m)*384 + j12 + 8] = qc;
      }
    }
    vph += 4; vbar(vbc, vph);
    {
      #pragma unroll
      for (int t = 0; t < 3; ++t) {
        const int idx = t*256 + vt;            // 0..767 == m*384+j
        const int m = idx / 384, j = idx - m*384;
        float gv = vs[VGX + idx];
        #pragma unroll
        for (int kq = 0; kq < 8; ++kq) gv += vs[VZ1 + (kq*2 + m)*384 + j];
        vs[VGATES + idx] = gv;
      }
    }
    vph += 4; vbar(vbc, vph);

    // ===== phase 6: pointwise LSTM (h,s stay in LDS) =====
    if (vt < 192) {
      const int m = vt / 96, hj = vt - m*96;
      const float gi = vs[VGATES + m*384 + hj];
      const float gf = vs[VGATES + m*384 + 96 + hj];
      const float gg = vs[VGATES + m*384 + 192 + hj];
      const float go = vs[VGATES + m*384 + 288 + hj];
      const float sv = vs[VSLC + vt];
      const float ig = 1.f/(1.f + expf(-gi));
      const float fg = 1.f/(1.f + expf(-gf));
      const float cg = tanhf(gg);
      const float og = 1.f/(1.f + expf(-go));
      const float s2 = fg*sv + ig*cg;
      const float h2 = og*tanhf(s2);
      vs[VSLC + vt] = s2;
      vs[VH2T + hj*2 + m] = h2;
      vs[VMSGH + (96+hj)*2 + m] = h2;   // h for next step's LSTM GEMM
    }
    vph += 4; vbar(vbc, vph);

    // ===== phase 7: u_next = h2 @ [W0_edge | W0_self] (float4 W, packed fma) =====
    {
      const int jg = vt & 15, kq = vt >> 4;   // j12 cols (192), kq 0..15 x 6k
      const int j12 = jg*12, k0 = kq*6;
      const float* Wb = (j12 < 96) ? (msg0_W + j12) : (msg0_W + 9216 + j12 - 96);
      v2f acc[2][6] = {};
      #pragma unroll
      for (int kk = 0; kk < 6; ++kk) {
        const int k = k0 + kk;
        const float2 iv = *(const float2*)&vs[VH2T + k*2];
        const float* wp = Wb + k*96;
        const float4 wa = *(const float4*)wp;
        const float4 wm = *(const float4*)(wp + 4);
        const float4 wc = *(const float4*)(wp + 8);
        const v2f w0 = {wa.x, wa.y}, w1 = {wa.z, wa.w};
        const v2f w2 = {wm.x, wm.y}, w3 = {wm.z, wm.w};
        const v2f w4 = {wc.x, wc.y}, w5 = {wc.z, wc.w};
        const v2f i0 = {iv.x, iv.x}, i1 = {iv.y, iv.y};
        acc[0][0] = PFMA(i0, w0, acc[0][0]);
        acc[0][1] = PFMA(i0, w1, acc[0][1]);
        acc[0][2] = PFMA(i0, w2, acc[0][2]);
        acc[0][3] = PFMA(i0, w3, acc[0][3]);
        acc[0][4] = PFMA(i0, w4, acc[0][4]);
        acc[0][5] = PFMA(i0, w5, acc[0][5]);
        acc[1][0] = PFMA(i1, w0, acc[1][0]);
        acc[1][1] = PFMA(i1, w1, acc[1][1]);
        acc[1][2] = PFMA(i1, w2, acc[1][2]);
        acc[1][3] = PFMA(i1, w3, acc[1][3]);
        acc[1][4] = PFMA(i1, w4, acc[1][4]);
        acc[1][5] = PFMA(i1, w5, acc[1][5]);
      }
      #pragma unroll
      for (int m = 0; m < 2; ++m) {
        float4 qa = {acc[m][0][0], acc[m][0][1], acc[m][1][0], acc[m][1][1]};
        float4 qb = {acc[m][2][0], acc[m][2][1], acc[m][3][0], acc[m][3][1]};
        float4 qc = {acc[m][4][0], acc[m][4][1], acc[m][5][0], acc[m][5][1]};
        *(float4*)&vs[VZ1 + (kq*2 + m)*192 + j12]     = qa;   // PU overlay
        *(float4*)&vs[VZ1 + (kq*2 + m)*192 + j12 + 4] = qb;
        *(float4*)&vs[VZ1 + (kq*2 + m)*192 + j12 + 8] = qc;
      }
    }
    vph += 4; vbar(vbc, vph);
    if (vt < 192) {
      #pragma unroll
      for (int t = 0; t < 2; ++t) {
        const int idx = t*192 + vt;            // 0..383
        const int m = idx / 192, j = idx - m*192;
        float v = (j >= 96) ? sm[M0B + j - 96] : 0.f;   // fold b0 into self half
        #pragma unroll
        for (int kq = 0; kq < 16; ++kq) v += vs[VZ1 + (kq*2 + m)*192 + j];
        uN[(gbase+m)*192 + j] = v;
      }
    } else {
      // pred head partials (wave 3 of vblock; h2t stable since phase 6; pred_W in LDS)
      const int t2 = vt - 192;
      const int m = t2 >> 5, c = (t2 >> 2) & 7, kq2 = t2 & 3;
      float p = 0.f;
      #pragma unroll
      for (int kk = 0; kk < 24; ++kk) {
        const int k = kq2*24 + kk;
        p = fmaf(vs[VH2T + k*2 + m], sm[PRW + k*8 + c], p);
      }
      p += __shfl_xor(p, 1);
      p += __shfl_xor(p, 2);
      if (kq2 == 0) vs[VLGT + m*8 + c] = p + pred_b[c];
    }
    vph += 4; vbar(vbc, vph);

    // ===== phase 8: softmax/loss/pred =====
    if (vt < 2) {
      const int m = vt;
      const int node = gbase + m;
      float mx = vs[VLGT + m*8];
      int pred = 0;
      #pragma unroll
      for (int c = 1; c < 8; ++c) {
        const float v = vs[VLGT + m*8 + c];
        if (v > mx) { mx = v; pred = c; }
      }
      float sum = 0.f;
      #pragma unroll
      for (int c = 0; c < 8; ++c) sum += expf(vs[VLGT + m*8 + c] - mx);
      const float lse = mx + logf(sum);
      const int tgt = target[node] - 1;
      vs[VLGT + 16 + m] = lse - vs[VLGT + m*8 + tgt];
      vs[VLGT + 20 + m] = (pred == tgt) ? 1.f : 0.f;
      if (st == NSTEPS-1) final_pred_out[node] = (float)pred;
      if (m == 0) {
        // lanes 0,1 of this wave wrote above; in-wave instruction order makes this safe
        lossP[st*512 + bb*32 + grp*2 + vb] = vs[VLGT+16] + vs[VLGT+17];
        cntP[st*512 + bb*32 + grp*2 + vb] = (int)(vs[VLGT+20] + vs[VLGT+21]);
      }
    }

    // ===== per-batch barrier (16 blocks), ONE fence per block (round-3 proven form) =====
    if (st < NSTEPS-1) {
      __syncthreads();   // joins both vblocks; drains vmcnt for all uN stores
      if (tid == 0) {
        __hip_atomic_fetch_add(&bar[bb*16], 1, __ATOMIC_RELEASE, __HIP_MEMORY_SCOPE_AGENT);
        const int want = 16*(st+1);
        while (__hip_atomic_load(&bar[bb*16], __ATOMIC_RELAXED, __HIP_MEMORY_SCOPE_AGENT) < want)
          __builtin_amdgcn_s_sleep(2);
        __threadfence();   // acquire before reading peers' u (single wave per block)
      }
      __syncthreads();
      const float* tp = uP; uP = uN; uN = (float*)tp;
    }
  }
}

// ---------------- finalize: accs + loss ----------------
__global__ void finalize_kernel(const float* __restrict__ lossP,
                                const int* __restrict__ cntP,
                                float* __restrict__ out)
{
  __shared__ float sl[32];
  const int tid = threadIdx.x;   // 256
  const int st = tid >> 3, q = tid & 7;
  float lsum = 0.f;
  for (int i = 0; i < 64; ++i) lsum += lossP[st*512 + q*64 + i];
  lsum += __shfl_xor(lsum, 1);
  lsum += __shfl_xor(lsum, 2);
  lsum += __shfl_xor(lsum, 4);
  if (q == 0) sl[st] = lsum;
  float okc = 0.f;
  #pragma unroll
  for (int t = 0; t < 2; ++t) {
    const int bbat = q + 8*t;                    // batch id
    int c = 0;
    for (int i = 0; i < 32; ++i) c += cntP[st*512 + bbat*32 + i];
    okc += (c == 64) ? 1.f : 0.f;
  }
  okc += __shfl_xor(okc, 1);
  okc += __shfl_xor(okc, 2);
  okc += __shfl_xor(okc, 4);
  if (q == 0) out[1 + st] = okc / 16.f;
  __syncthreads();
  if (tid == 0) {
    float tot = 0.f;
    for (int i = 0; i < 32; ++i) tot += sl[i];
    out[0] = tot / (1024.f * (float)NSTEPS);
  }
}

extern "C" void kernel_launch(void* const* d_in, const int* in_sizes, int n_in,
                              void* d_out, int out_size, void* d_ws, size_t ws_size,
                              hipStream_t stream) {
  const int*   x         = (const int*)  d_in[0];
  const int*   target    = (const int*)  d_in[1];
  const int*   edges     = (const int*)  d_in[2];
  const float* digit_emb = (const float*)d_in[3];
  const float* row_emb   = (const float*)d_in[4];
  const float* col_emb   = (const float*)d_in[5];
  const float* in0_W     = (const float*)d_in[6];
  const float* in0_b     = (const float*)d_in[7];
  const float* in_Ws     = (const float*)d_in[8];
  const float* in_bs     = (const float*)d_in[9];
  const float* msg0_W    = (const float*)d_in[10];
  const float* msg0_b    = (const float*)d_in[11];
  const float* msg_Ws    = (const float*)d_in[12];
  const float* msg_bs    = (const float*)d_in[13];
  const float* W_ih      = (const float*)d_in[14];
  const float* W_hh      = (const float*)d_in[15];
  const float* b_ih      = (const float*)d_in[16];
  const float* b_hh      = (const float*)d_in[17];
  const float* pred_W    = (const float*)d_in[18];
  const float* pred_b    = (const float*)d_in[19];

  float* ws    = (float*)d_ws;
  float* u0    = ws + WS_U0;
  int*   bar   = (int*)(ws + WS_BAR);
  float* u1    = ws + WS_U1;
  float* xin   = ws + WS_XIN;
  float* gxb   = ws + WS_GX;
  float* lossP = ws + WS_LOSSP;
  int*   cntP  = (int*)(ws + WS_CNTP);

  // zero u0 (edge halves) + barrier counters; everything else fully written
  hipMemsetAsync(d_ws, 0, (size_t)(196608 + 256)*sizeof(float), stream);

  init_kernel<<<1024, HD, 0, stream>>>(x, digit_emb, row_emb, col_emb,
                                       in0_W, in0_b, in_Ws, in_bs,
                                       msg0_b, xin, u0);
  gx_kernel<<<256, 384, 0, stream>>>(xin, W_ih, b_ih, b_hh, gxb);

  float* outp = (float*)d_out;
  solve_kernel<<<256, 512, 0, stream>>>(
      edges, msg0_W, msg0_b, msg_Ws, msg_bs,
      W_ih, W_hh, pred_W, pred_b, target, gxb,
      u0, u1, bar, lossP, cntP, outp + 1 + NSTEPS);

  finalize_kernel<<<1, 256, 0, stream>>>(lossP, cntP, outp);
}

// Round 7
// 1044.012 us; speedup vs baseline: 2.0681x; 1.1391x over previous
//
#include <hip/hip_runtime.h>

#define DEG 17
#define NSTEPS 32
#define HD 96

// ---- workspace float offsets ----
#define WS_U0     0          // 196608
#define WS_BAR    196608     // 256 ints (16 counters spaced 16 apart)
#define WS_U1     196864     // 196608
#define WS_XIN    393472     // 98304
#define WS_GX     491776     // 393216
#define WS_LOSSP  884992     // 8192 floats (32 steps * 256)
#define WS_CNTP   901376     // 8192 ints

// ---- LDS layout (floats) ----
#define W1L    0        // 9216  [96][96]
#define W2L    9216     // 9216  [96][96]
#define MSGB   18432    // 288
#define M0B    18720    // 96
#define PRW    18816    // 768  pred_W [96][8]
#define MSGH4  19584    // 768  [192][4] (msg k<96, h k>=96; h persists across steps)
#define GATES4 20352    // 1536 [4][384]
#define H2T4   21888    // 384  [96][4]
#define SLC4   22272    // 384  [4][96] cell state (persistent)
#define GX4    22656    // 1536 [4][384]
#define LGT    24192    // 32
#define NBRI   24224    // 80 ints
#define BARC   24304    // 2 ints (vblock barrier counters)
#define VBASE  24320
#define VSTR   7888     // 16-float bank stagger between vblocks
// per-vblock relative offsets:
#define VZ1    0        // 3840 [96][40]; overlay: phase-4a P3[16][96], phase-5 PL[32][192], phase-7 PU[64][96]
#define VZ2    3840     // 3840 [96][40]  (PL/PU overflow into here; dead after phase 3)
#define VS3T   7680     // 192  [96][2]
#define SMTOT  (VBASE + 2*VSTR)   // 40096 floats = 160384 B (<= 160 KiB)

// ---------------- init1: embedding + input MLP -> xin; u0 self-half = msg0_b
__global__ void init_kernel(
    const int* __restrict__ x,
    const float* __restrict__ digit_emb,
    const float* __restrict__ row_emb,
    const float* __restrict__ col_emb,
    const float* __restrict__ in0_W,
    const float* __restrict__ in0_b,
    const float* __restrict__ in_Ws,
    const float* __restrict__ in_bs,
    const float* __restrict__ msg0_b,
    float* __restrict__ xin,
    float* __restrict__ u0)
{
  const int node = blockIdx.x;
  const int j = threadIdx.x;
  const int n = node & 63;
  const int r = n >> 3, c = n & 7;
  __shared__ float feat[48];
  __shared__ float za[HD];
  __shared__ float zb[HD];
  if (j < 16)      feat[j] = digit_emb[x[node]*16 + j];
  else if (j < 32) feat[j] = row_emb[r*16 + (j-16)];
  else if (j < 48) feat[j] = col_emb[c*16 + (j-32)];
  u0[node*192 + 96 + j] = msg0_b[j];
  __syncthreads();
  float a = in0_b[j];
  for (int k = 0; k < 48; ++k) a = fmaf(feat[k], in0_W[k*HD + j], a);
  za[j] = fmaxf(a, 0.f);
  __syncthreads();
  a = in_bs[j];
  for (int k = 0; k < HD; ++k) a = fmaf(za[k], in_Ws[k*HD + j], a);
  zb[j] = fmaxf(a, 0.f);
  __syncthreads();
  a = in_bs[HD + j];
  for (int k = 0; k < HD; ++k) a = fmaf(zb[k], in_Ws[9216 + k*HD + j], a);
  za[j] = fmaxf(a, 0.f);
  __syncthreads();
  a = in_bs[2*HD + j];
  for (int k = 0; k < HD; ++k) a = fmaf(za[k], in_Ws[2*9216 + k*HD + j], a);
  xin[node*HD + j] = a;
}

// ---------------- init2: gx = xin @ W_ih[96:192] + b_ih + b_hh (one-time)
__global__ __launch_bounds__(384) void gx_kernel(
    const float* __restrict__ xin, const float* __restrict__ W_ih,
    const float* __restrict__ b_ih, const float* __restrict__ b_hh,
    float* __restrict__ gx)
{
  __shared__ float xs[4*HD];
  const int tid = threadIdx.x;
  const int base = blockIdx.x * 4;
  {
    const int m = tid / HD, k = tid - m*HD;
    xs[m*HD + k] = xin[(base+m)*HD + k];
  }
  __syncthreads();
  const int j = tid;  // 0..383
  float a0 = b_ih[j] + b_hh[j], a1 = a0, a2 = a0, a3 = a0;
  for (int k = 0; k < HD; ++k) {
    const float w = W_ih[(96+k)*384 + j];
    a0 = fmaf(xs[k], w, a0);
    a1 = fmaf(xs[HD+k], w, a1);
    a2 = fmaf(xs[2*HD+k], w, a2);
    a3 = fmaf(xs[3*HD+k], w, a3);
  }
  gx[(base+0)*384 + j] = a0;
  gx[(base+1)*384 + j] = a1;
  gx[(base+2)*384 + j] = a2;
  gx[(base+3)*384 + j] = a3;
}

// per-vblock barrier over 4 waves: LDS counter, monotonically increasing target
__device__ __forceinline__ void vbar(int* c, int want) {
  if ((threadIdx.x & 63) == 0)
    __hip_atomic_fetch_add(c, 1, __ATOMIC_RELEASE, __HIP_MEMORY_SCOPE_WORKGROUP);
  while (__hip_atomic_load(c, __ATOMIC_ACQUIRE, __HIP_MEMORY_SCOPE_WORKGROUP) < want)
    __builtin_amdgcn_s_sleep(1);
}

// ---------------- persistent solver: 256 blocks (1/CU) ----------------
// phases 1-4: 2 vblocks x 4 waves, 2 nodes each (decoupled, own barriers)
// phases 5-8: block-wide, j-columns split across vblocks (weights read once/block)
__global__ __launch_bounds__(512, 1) void solve_kernel(
    const int* __restrict__ edges,
    const float* __restrict__ msg0_W, const float* __restrict__ msg0_b,
    const float* __restrict__ msg_Ws, const float* __restrict__ msg_bs,
    const float* __restrict__ W_ih, const float* __restrict__ W_hh,
    const float* __restrict__ pred_W, const float* __restrict__ pred_b,
    const int* __restrict__ target,
    const float* __restrict__ gx,
    float* __restrict__ u0, float* __restrict__ u1,
    int* bar,
    float* __restrict__ lossP, int* __restrict__ cntP,
    float* __restrict__ final_pred_out)
{
  __shared__ float sm[SMTOT];

  const int tid = threadIdx.x;
  const int vb  = tid >> 8;          // vblock 0/1
  const int vt  = tid & 255;         // thread-in-vblock
  const int blk = blockIdx.x;
  const int bb  = blk & 15;          // batch; blocks == bb (mod 16)
  const int grp = blk >> 4;
  const int base = bb*64 + grp*4;    // first node of block (4 nodes)

  float* const vs = sm + VBASE + vb*VSTR;
  int* const nbrs = (int*)(sm + NBRI);
  int* const vbc = (int*)(sm + BARC) + vb;

  // ===== one-time LDS fill =====
  for (int i = tid*4; i < 9216; i += 2048) {
    *(float4*)&sm[W1L + i] = *(const float4*)&msg_Ws[i];
    *(float4*)&sm[W2L + i] = *(const float4*)&msg_Ws[9216 + i];
  }
  if (tid < 288) sm[MSGB + tid] = msg_bs[tid];
  if (tid < 96)  sm[M0B + tid]  = msg0_b[tid];
  if (tid < 2)   ((int*)(sm + BARC))[tid] = 0;
  for (int i = tid; i < 768; i += 512) sm[PRW + i] = pred_W[i];
  #pragma unroll
  for (int t = 0; t < 3; ++t) {
    const int idx = t*512 + tid;     // 0..1535
    sm[GX4 + idx] = gx[base*384 + idx];
  }
  if (tid < 384) {
    sm[SLC4 + tid] = 0.f;            // cell state [4][96]
    sm[MSGH4 + 384 + tid] = 0.f;     // h slots (k=96..191)
  }
  if (tid < 80) {
    const int m = tid / 20, r = tid % 20;
    nbrs[tid] = (r < DEG) ? (bb*64 + edges[(grp*4 + m)*DEG + r])*192 : -1;
  }
  __syncthreads();

  const float* uP = u0;
  float*       uN = u1;
  int vph = 0;

  for (int st = 0; st < NSTEPS; ++st) {
    // ===== phase 1 (per-vblock): z1 gather (240 thr) + s3t zero (16 thr) =====
    if (vt < 240) {
      const int row = vt % 40;       // m*20 + r (m local 0/1)
      const int kh  = vt / 40;       // 0..5
      const int m = row / 20;
      const int k0 = kh * 16;
      const int nb = nbrs[vb*40 + row];
      if (nb >= 0) {
        const float* ue = uP + nb + k0;
        const float* us = uP + (base + vb*2 + m)*192 + 96 + k0;
        #pragma unroll
        for (int t = 0; t < 4; ++t) {
          const float4 a = *(const float4*)(ue + 4*t);
          const float4 b = *(const float4*)(us + 4*t);
          vs[VZ1 + (k0+4*t+0)*40 + row] = fmaxf(a.x + b.x, 0.f);
          vs[VZ1 + (k0+4*t+1)*40 + row] = fmaxf(a.y + b.y, 0.f);
          vs[VZ1 + (k0+4*t+2)*40 + row] = fmaxf(a.z + b.z, 0.f);
          vs[VZ1 + (k0+4*t+3)*40 + row] = fmaxf(a.w + b.w, 0.f);
        }
      } else {
        #pragma unroll
        for (int t = 0; t < 16; ++t) vs[VZ1 + (k0+t)*40 + row] = 0.f;
      }
    } else {
      const int i = vt - 240;        // 16 threads zero VS3T[192]
      #pragma unroll
      for (int t = 0; t < 12; ++t) vs[VS3T + i*12 + t] = 0.f;
    }
    vph += 4; vbar(vbc, vph);

    // ===== phase 2 (per-vblock): GEMM1 z2 = relu(z1 @ W1 + b1), LDS W =====
    if (vt < 240) {
      const int jg = vt % 24, dg = vt / 24;   // 4 cols, 4 rows
      const int j4 = jg*4, d4 = dg*4;
      float acc[4][4] = {{0.f}};
      #pragma unroll 4
      for (int k = 0; k < 96; ++k) {
        const float4 z = *(const float4*)&vs[VZ1 + k*40 + d4];
        const float4 w = *(const float4*)&sm[W1L + k*96 + j4];
        const float ze[4] = {z.x, z.y, z.z, z.w};
        const float we[4] = {w.x, w.y, w.z, w.w};
        #pragma unroll
        for (int dd = 0; dd < 4; ++dd)
          #pragma unroll
          for (int jj = 0; jj < 4; ++jj)
            acc[dd][jj] = fmaf(ze[dd], we[jj], acc[dd][jj]);
      }
      #pragma unroll
      for (int jj = 0; jj < 4; ++jj) {
        const float b1 = sm[MSGB + j4 + jj];
        float4 q;
        q.x = fmaxf(acc[0][jj] + b1, 0.f);
        q.y = fmaxf(acc[1][jj] + b1, 0.f);
        q.z = fmaxf(acc[2][jj] + b1, 0.f);
        q.w = fmaxf(acc[3][jj] + b1, 0.f);
        *(float4*)&vs[VZ2 + (j4+jj)*40 + d4] = q;
      }
    }
    vph += 4; vbar(vbc, vph);

    // ===== phase 3 (per-vblock): GEMM2 + relu + masked row-sum -> s3t =====
    if (vt < 240) {
      const int jg = vt % 24, dg = vt / 24;
      const int j4 = jg*4, d4 = dg*4;
      float acc[4][4] = {{0.f}};
      #pragma unroll 4
      for (int k = 0; k < 96; ++k) {
        const float4 z = *(const float4*)&vs[VZ2 + k*40 + d4];
        const float4 w = *(const float4*)&sm[W2L + k*96 + j4];
        const float ze[4] = {z.x, z.y, z.z, z.w};
        const float we[4] = {w.x, w.y, w.z, w.w};
        #pragma unroll
        for (int dd = 0; dd < 4; ++dd)
          #pragma unroll
          for (int jj = 0; jj < 4; ++jj)
            acc[dd][jj] = fmaf(ze[dd], we[jj], acc[dd][jj]);
      }
      const int nd = d4 / 20;        // rows d4..d4+3 never straddle a node
      const int r0 = d4 - nd*20;
      #pragma unroll
      for (int jj = 0; jj < 4; ++jj) {
        const float b2 = sm[MSGB + 96 + j4 + jj];
        float p = 0.f;
        #pragma unroll
        for (int dd = 0; dd < 4; ++dd)
          if (r0 + dd < DEG) p += fmaxf(acc[dd][jj] + b2, 0.f);
        atomicAdd(&vs[VS3T + (j4+jj)*2 + nd], p);
      }
    }
    vph += 4; vbar(vbc, vph);

    // ===== phase 4a (per-vblock): GEMM3 partials (stream W3, own 2 nodes) =====
    if (vt < 192) {
      const int jg = vt % 24, kq = vt / 24;   // kq 0..7, 12 k each
      const int j4 = jg*4, k0 = kq*12;
      const float* W3 = msg_Ws + 2*9216;
      float acc[2][4] = {{0.f}};
      #pragma unroll
      for (int kk = 0; kk < 12; ++kk) {
        const int k = k0 + kk;
        const float2 sv = *(const float2*)&vs[VS3T + k*2];
        const float4 wv = *(const float4*)&W3[k*96 + j4];
        const float se[2] = {sv.x, sv.y};
        const float we[4] = {wv.x, wv.y, wv.z, wv.w};
        #pragma unroll
        for (int m = 0; m < 2; ++m)
          #pragma unroll
          for (int jj = 0; jj < 4; ++jj)
            acc[m][jj] = fmaf(se[m], we[jj], acc[m][jj]);
      }
      #pragma unroll
      for (int m = 0; m < 2; ++m) {
        float4 q = {acc[m][0], acc[m][1], acc[m][2], acc[m][3]};
        *(float4*)&vs[VZ1 + (kq*2 + m)*96 + j4] = q;    // P3 overlay
      }
    }
    vph += 4; vbar(vbc, vph);
    // ===== phase 4b (per-vblock): reduce -> shared msgh columns (own m) =====
    if (vt < 192) {
      const int m = vt / 96, j = vt % 96;
      float v = 17.f * sm[MSGB + 192 + j];
      #pragma unroll
      for (int kq = 0; kq < 8; ++kq) v += vs[VZ1 + (kq*2 + m)*96 + j];
      sm[MSGH4 + j*4 + vb*2 + m] = v;
    }
    __syncthreads();   // join both vblocks; MSGH4 complete

    // ===== phase 5 (block-wide, j-split): gates partials, W read once/block =====
    {
      const int jg = vt & 31, kq = vt >> 5;   // 6 cols, kq 0..7 x 24k
      const int j6 = vb*192 + jg*6;           // global gate column
      const int jl = jg*6;                    // column within this vblock's half
      const int k0 = kq*24;
      const float* Wb = (kq < 4) ? (W_ih + (size_t)k0*384 + j6)
                                 : (W_hh + (size_t)(k0-96)*384 + j6);
      float acc[4][6] = {{0.f}};
      #pragma unroll 4
      for (int kk = 0; kk < 24; ++kk) {
        const float4 mv = *(const float4*)&sm[MSGH4 + (k0+kk)*4];  // 4 nodes (broadcast)
        const float* wp = Wb + (size_t)kk*384;
        const float2 wa = *(const float2*)wp;
        const float2 wb2 = *(const float2*)(wp + 2);
        const float2 wc = *(const float2*)(wp + 4);
        const float me[4] = {mv.x, mv.y, mv.z, mv.w};
        const float we[6] = {wa.x, wa.y, wb2.x, wb2.y, wc.x, wc.y};
        #pragma unroll
        for (int m = 0; m < 4; ++m)
          #pragma unroll
          for (int jj = 0; jj < 6; ++jj)
            acc[m][jj] = fmaf(me[m], we[jj], acc[m][jj]);
      }
      #pragma unroll
      for (int m = 0; m < 4; ++m) {           // PL overlay in own vblock region
        float2 qa = {acc[m][0], acc[m][1]};
        float2 qb = {acc[m][2], acc[m][3]};
        float2 qc = {acc[m][4], acc[m][5]};
        *(float2*)&vs[VZ1 + (kq*4 + m)*192 + jl]     = qa;
        *(float2*)&vs[VZ1 + (kq*4 + m)*192 + jl + 2] = qb;
        *(float2*)&vs[VZ1 + (kq*4 + m)*192 + jl + 4] = qc;
      }
    }
    __syncthreads();
    {  // gates reduce (512 thr x 3 entries)
      #pragma unroll
      for (int t = 0; t < 3; ++t) {
        const int idx = t*512 + tid;          // 0..1535 == m*384 + j
        const int m = idx / 384, j = idx - m*384;
        const int vbh = (j >= 192) ? 1 : 0;
        const int jl = j - vbh*192;
        const float* pb = sm + VBASE + vbh*VSTR;
        float g = sm[GX4 + idx];
        #pragma unroll
        for (int kq = 0; kq < 8; ++kq) g += pb[VZ1 + (kq*4 + m)*192 + jl];
        sm[GATES4 + idx] = g;
      }
    }
    __syncthreads();

    // ===== phase 6 (block-wide): pointwise LSTM =====
    if (tid < 384) {
      const int m = tid / 96, hj = tid - m*96;
      const float gi = sm[GATES4 + m*384 + hj];
      const float gf = sm[GATES4 + m*384 + 96 + hj];
      const float gg = sm[GATES4 + m*384 + 192 + hj];
      const float go = sm[GATES4 + m*384 + 288 + hj];
      const float sv = sm[SLC4 + tid];
      const float ig = 1.f/(1.f + expf(-gi));
      const float fg = 1.f/(1.f + expf(-gf));
      const float cg = tanhf(gg);
      const float og = 1.f/(1.f + expf(-go));
      const float s2 = fg*sv + ig*cg;
      const float h2 = og*tanhf(s2);
      sm[SLC4 + tid] = s2;
      sm[H2T4 + hj*4 + m] = h2;
      sm[MSGH4 + (96+hj)*4 + m] = h2;   // h for next step's LSTM GEMM
    }
    __syncthreads();

    // ===== phase 7 (block-wide, j-split): u partials, msg0_W read once/block =====
    {
      const int jg = vt & 15, kq = vt >> 4;   // 6 cols, kq 0..15 x 6k
      const int j6 = jg*6;                    // column within this vblock's half
      const float* Wb = (vb == 0) ? (msg0_W + j6) : (msg0_W + 9216 + j6);
      const int k0 = kq*6;
      float acc[4][6] = {{0.f}};
      #pragma unroll
      for (int kk = 0; kk < 6; ++kk) {
        const int k = k0 + kk;
        const float4 hv = *(const float4*)&sm[H2T4 + k*4];   // 4 nodes (broadcast)
        const float* wp = Wb + k*96;
        const float2 wa = *(const float2*)wp;
        const float2 wb2 = *(const float2*)(wp + 2);
        const float2 wc = *(const float2*)(wp + 4);
        const float he[4] = {hv.x, hv.y, hv.z, hv.w};
        const float we[6] = {wa.x, wa.y, wb2.x, wb2.y, wc.x, wc.y};
        #pragma unroll
        for (int m = 0; m < 4; ++m)
          #pragma unroll
          for (int jj = 0; jj < 6; ++jj)
            acc[m][jj] = fmaf(he[m], we[jj], acc[m][jj]);
      }
      #pragma unroll
      for (int m = 0; m < 4; ++m) {           // PU overlay in own vblock region
        float2 qa = {acc[m][0], acc[m][1]};
        float2 qb = {acc[m][2], acc[m][3]};
        float2 qc = {acc[m][4], acc[m][5]};
        *(float2*)&vs[VZ1 + (kq*4 + m)*96 + j6]     = qa;
        *(float2*)&vs[VZ1 + (kq*4 + m)*96 + j6 + 2] = qb;
        *(float2*)&vs[VZ1 + (kq*4 + m)*96 + j6 + 4] = qc;
      }
    }
    __syncthreads();
    if (tid < 384) {   // u-write reduce (2 entries each)
      #pragma unroll
      for (int t = 0; t < 2; ++t) {
        const int idx = t*384 + tid;          // 0..767 == m*192 + j
        const int m = idx / 192, j = idx - m*192;
        const int vbh = (j >= 96) ? 1 : 0;
        const int jl = j - vbh*96;
        const float* pb = sm + VBASE + vbh*VSTR;
        float v = vbh ? sm[M0B + jl] : 0.f;   // fold b0 into self half
        #pragma unroll
        for (int kq = 0; kq < 16; ++kq) v += pb[VZ1 + (kq*4 + m)*96 + jl];
        uN[(base+m)*192 + j] = v;
      }
    } else {
      // pred head partials (threads 384..511; h2t4 stable since phase 6)
      const int t2 = tid - 384;
      const int m = t2 >> 5, c = (t2 >> 2) & 7, kq2 = t2 & 3;
      float p = 0.f;
      #pragma unroll
      for (int kk = 0; kk < 24; ++kk) {
        const int k = kq2*24 + kk;
        p = fmaf(sm[H2T4 + k*4 + m], sm[PRW + k*8 + c], p);
      }
      p += __shfl_xor(p, 1);
      p += __shfl_xor(p, 2);
      if (kq2 == 0) sm[LGT + m*8 + c] = p + pred_b[c];
    }
    __syncthreads();

    // ===== phase 8: softmax/loss/pred =====
    if (tid < 4) {
      const int m = tid;
      const int node = base + m;
      float mx = sm[LGT + m*8];
      int pred = 0;
      #pragma unroll
      for (int c = 1; c < 8; ++c) {
        const float v = sm[LGT + m*8 + c];
        if (v > mx) { mx = v; pred = c; }
      }
      float sum = 0.f;
      #pragma unroll
      for (int c = 0; c < 8; ++c) sum += expf(sm[LGT + m*8 + c] - mx);
      const float lse = mx + logf(sum);
      const int tgt = target[node] - 1;
      sm[LGT + 16 + m] = lse - sm[LGT + m*8 + tgt];
      sm[LGT + 20 + m] = (pred == tgt) ? 1.f : 0.f;
      if (st == NSTEPS-1) final_pred_out[node] = (float)pred;
      if (m == 0) {
        // lanes 0..3 of this wave wrote above; in-wave order makes this safe
        lossP[st*256 + blk] = sm[LGT+16] + sm[LGT+17] + sm[LGT+18] + sm[LGT+19];
        cntP[st*256 + blk] = (int)(sm[LGT+20] + sm[LGT+21] + sm[LGT+22] + sm[LGT+23]);
      }
    }

    // ===== per-batch barrier (16 blocks), ONE fence per block =====
    if (st < NSTEPS-1) {
      __syncthreads();   // drains vmcnt for all uN stores
      if (tid == 0) {
        __hip_atomic_fetch_add(&bar[bb*16], 1, __ATOMIC_RELEASE, __HIP_MEMORY_SCOPE_AGENT);
        const int want = 16*(st+1);
        while (__hip_atomic_load(&bar[bb*16], __ATOMIC_RELAXED, __HIP_MEMORY_SCOPE_AGENT) < want)
          __builtin_amdgcn_s_sleep(2);
        __threadfence();   // acquire before reading peers' u (single wave per block)
      }
      __syncthreads();
      const float* tp = uP; uP = uN; uN = (float*)tp;
    }
  }
}

// ---------------- finalize: accs + loss ----------------
__global__ void finalize_kernel(const float* __restrict__ lossP,
                                const int* __restrict__ cntP,
                                float* __restrict__ out)
{
  __shared__ float sl[32];
  const int tid = threadIdx.x;   // 256
  const int st = tid >> 3, q = tid & 7;
  float lsum = 0.f;
  for (int i = 0; i < 32; ++i) lsum += lossP[st*256 + q*32 + i];
  lsum += __shfl_xor(lsum, 1);
  lsum += __shfl_xor(lsum, 2);
  lsum += __shfl_xor(lsum, 4);
  if (q == 0) sl[st] = lsum;
  float okc = 0.f;
  #pragma unroll
  for (int t = 0; t < 2; ++t) {
    const int bbat = q + 8*t;                    // batch id
    int c = 0;
    for (int i = 0; i < 16; ++i) c += cntP[st*256 + i*16 + bbat];  // blocks ≡ bbat (mod 16)
    okc += (c == 64) ? 1.f : 0.f;
  }
  okc += __shfl_xor(okc, 1);
  okc += __shfl_xor(okc, 2);
  okc += __shfl_xor(okc, 4);
  if (q == 0) out[1 + st] = okc / 16.f;
  __syncthreads();
  if (tid == 0) {
    float tot = 0.f;
    for (int i = 0; i < 32; ++i) tot += sl[i];
    out[0] = tot / (1024.f * (float)NSTEPS);
  }
}

extern "C" void kernel_launch(void* const* d_in, const int* in_sizes, int n_in,
                              void* d_out, int out_size, void* d_ws, size_t ws_size,
                              hipStream_t stream) {
  const int*   x         = (const int*)  d_in[0];
  const int*   target    = (const int*)  d_in[1];
  const int*   edges     = (const int*)  d_in[2];
  const float* digit_emb = (const float*)d_in[3];
  const float* row_emb   = (const float*)d_in[4];
  const float* col_emb   = (const float*)d_in[5];
  const float* in0_W     = (const float*)d_in[6];
  const float* in0_b     = (const float*)d_in[7];
  const float* in_Ws     = (const float*)d_in[8];
  const float* in_bs     = (const float*)d_in[9];
  const float* msg0_W    = (const float*)d_in[10];
  const float* msg0_b    = (const float*)d_in[11];
  const float* msg_Ws    = (const float*)d_in[12];
  const float* msg_bs    = (const float*)d_in[13];
  const float* W_ih      = (const float*)d_in[14];
  const float* W_hh      = (const float*)d_in[15];
  const float* b_ih      = (const float*)d_in[16];
  const float* b_hh      = (const float*)d_in[17];
  const float* pred_W    = (const float*)d_in[18];
  const float* pred_b    = (const float*)d_in[19];

  float* ws    = (float*)d_ws;
  float* u0    = ws + WS_U0;
  int*   bar   = (int*)(ws + WS_BAR);
  float* u1    = ws + WS_U1;
  float* xin   = ws + WS_XIN;
  float* gxb   = ws + WS_GX;
  float* lossP = ws + WS_LOSSP;
  int*   cntP  = (int*)(ws + WS_CNTP);

  // zero u0 (edge halves) + barrier counters; everything else fully written
  hipMemsetAsync(d_ws, 0, (size_t)(196608 + 256)*sizeof(float), stream);

  init_kernel<<<1024, HD, 0, stream>>>(x, digit_emb, row_emb, col_emb,
                                       in0_W, in0_b, in_Ws, in_bs,
                                       msg0_b, xin, u0);
  gx_kernel<<<256, 384, 0, stream>>>(xin, W_ih, b_ih, b_hh, gxb);

  float* outp = (float*)d_out;
  solve_kernel<<<256, 512, 0, stream>>>(
      edges, msg0_W, msg0_b, msg_Ws, msg_bs,
      W_ih, W_hh, pred_W, pred_b, target, gxb,
      u0, u1, bar, lossP, cntP, outp + 1 + NSTEPS);

  finalize_kernel<<<1, 256, 0, stream>>>(lossP, cntP, outp);
}